// Round 5
// baseline (119.459 us; speedup 1.0000x reference)
//
#include <hip/hip_runtime.h>

#define D 8
#define NE 4
#define NS 3
#define NI 5
#define LN_EPS 1e-5f

// ---- wlds (weights-in-LDS) float offsets; all float4-sections 16B aligned ----
#define OFF_W1   0      // NS*64  = 192
#define OFF_W2   192    // NS*32  = 96
#define OFF_B1   288    // NS*8   = 24
#define OFF_B2   312    // NS*4   = 12
#define OFF_C    324    // NS*32  = 96
#define OFF_WP   420    // NS*512 = 1536
#define OFF_LNG  1956   // 8
#define OFF_LNB  1964   // 8
#define OFF_WOUT 1972   // 128
#define OFF_BOUT 2100   // 4
#define OFF_FG   2104   // 8
#define OFF_FB   2112   // 8
#define OFF_WCST 2120   // 144
#define OFF_BCST 2264   // 18
#define OFF_WCL  2284   // 8
#define OFF_BCL  2292   // 1
#define WLDS_SIZE 2296

// ---------------------------------------------------------------------------
// Setup kernel: C[s][n][d] = bproj[s][d] + sum_ij Bmat[s][n][i][j]*Wproj[s][d][i*8+j]
// ---------------------------------------------------------------------------
__global__ void precompute_C_kernel(const float* __restrict__ Bmat,
                                    const float* __restrict__ Wproj,
                                    const float* __restrict__ bproj,
                                    float* __restrict__ C) {
    int idx = threadIdx.x;
    if (idx >= NS * NE * D) return;
    int s = idx / (NE * D);
    int rem = idx % (NE * D);
    int n = rem / D;
    int d = rem % D;
    const float* bm = Bmat + ((size_t)s * NE + n) * 64;
    const float* wp = Wproj + ((size_t)s * D + d) * 64;
    float acc = bproj[s * D + d];
    #pragma unroll
    for (int k = 0; k < 64; ++k) acc += bm[k] * wp[k];
    C[idx] = acc;
}

__device__ __forceinline__ float fast_tanh(float x) {
    float e = __expf(2.f * x);
    return 1.f - 2.f * __builtin_amdgcn_rcpf(e + 1.f);
}

// ---------------------------------------------------------------------------
// Main kernel. Key idea: NO SMEM (s_load) in the hot loop. All loop weights
// live in LDS (ds_read -> VGPR, in-order returns -> fine-grained lgkmcnt,
// no 102-SGPR cap, no lgkmcnt(0) drains). W1 explicitly register-cached per
// stage; W2/B1/B2/Cs stream as uniform-broadcast ds_read_b128. t in regs.
// ---------------------------------------------------------------------------
__global__ __launch_bounds__(256, 2) void whisp_kernel(
    const float* __restrict__ cl, const float* __restrict__ cd,
    const float* __restrict__ re_log, const float* __restrict__ mach,
    const float* __restrict__ alpha, const float* __restrict__ u,
    const float* __restrict__ We, const float* __restrict__ be,
    const float* __restrict__ Wproj,
    const float* __restrict__ Wr1, const float* __restrict__ br1,
    const float* __restrict__ Wr2, const float* __restrict__ br2,
    const float* __restrict__ ln_g, const float* __restrict__ ln_b,
    const float* __restrict__ Wout, const float* __restrict__ bout,
    const float* __restrict__ fg, const float* __restrict__ fb,
    const float* __restrict__ Wcst, const float* __restrict__ bcst,
    const float* __restrict__ Wcl, const float* __restrict__ bcl,
    const float* __restrict__ Cpre,
    float* __restrict__ out, int B)
{
    __shared__ __align__(16) float wlds[WLDS_SIZE];
    __shared__ float souts[256 * 19];

    const int tid = threadIdx.x;
    const int row0 = blockIdx.x * 256 + tid;
    const bool active = (row0 < B);
    const int row = active ? row0 : (B - 1);

    // ---- stage all loop weights into LDS (one time, cooperative) ----
    for (int i = tid; i < 192;  i += 256) wlds[OFF_W1 + i]   = Wr1[i];
    for (int i = tid; i < 96;   i += 256) wlds[OFF_W2 + i]   = Wr2[i];
    for (int i = tid; i < 24;   i += 256) wlds[OFF_B1 + i]   = br1[i];
    for (int i = tid; i < 12;   i += 256) wlds[OFF_B2 + i]   = br2[i];
    for (int i = tid; i < 96;   i += 256) wlds[OFF_C + i]    = Cpre[i];
    for (int i = tid; i < 1536; i += 256) wlds[OFF_WP + i]   = Wproj[i];
    for (int i = tid; i < 8;    i += 256) { wlds[OFF_LNG + i] = ln_g[i]; wlds[OFF_LNB + i] = ln_b[i]; }
    for (int i = tid; i < 128;  i += 256) wlds[OFF_WOUT + i] = Wout[i];
    for (int i = tid; i < 4;    i += 256) wlds[OFF_BOUT + i] = bout[i];
    for (int i = tid; i < 8;    i += 256) { wlds[OFF_FG + i] = fg[i]; wlds[OFF_FB + i] = fb[i]; }
    for (int i = tid; i < 144;  i += 256) wlds[OFF_WCST + i] = Wcst[i];
    for (int i = tid; i < 18;   i += 256) wlds[OFF_BCST + i] = bcst[i];
    for (int i = tid; i < 8;    i += 256) wlds[OFF_WCL + i]  = Wcl[i];
    for (int i = tid; i < 1;    i += 256) wlds[OFF_BCL + i]  = bcl[i];

    // ---- per-row inputs (overlap with LDS staging) ----
    float uu[D];
    {
        const float4* up = reinterpret_cast<const float4*>(u + (size_t)row * D);
        float4 u0 = up[0], u1 = up[1];
        uu[0] = u0.x; uu[1] = u0.y; uu[2] = u0.z; uu[3] = u0.w;
        uu[4] = u1.x; uu[5] = u1.y; uu[6] = u1.z; uu[7] = u1.w;
    }
    float xs[NE] = { cl[row], cd[row], re_log[row], mach[row] };
    float al = alpha[row];

    // ---- embedding (We/be: one-time uniform global loads, outside hot loop) ----
    float E[NE][D];
    #pragma unroll
    for (int n = 0; n < NE; ++n) {
        #pragma unroll
        for (int d = 0; d < D; ++d) {
            float pre = We[n * 16 + d * 2 + 0] * xs[n]
                      + We[n * 16 + d * 2 + 1] * al
                      + be[n * D + d];
            E[n][d] = fast_tanh(pre);
        }
    }

    __syncthreads();   // wlds ready

    const float4* wlds4 = reinterpret_cast<const float4*>(wlds);

    // ---- outer stages ----
    #pragma unroll
    for (int s = 0; s < NS; ++s) {
        // t[d][i] = sum_j u[j]*Wp[d][i*8+j]   (Wp via LDS b128 broadcast)
        float t[D][D];
        #pragma unroll
        for (int d = 0; d < D; ++d) {
            #pragma unroll
            for (int i = 0; i < D; ++i) {
                float4 wa = wlds4[(OFF_WP + s * 512 + d * 64 + i * 8) / 4];
                float4 wb = wlds4[(OFF_WP + s * 512 + d * 64 + i * 8) / 4 + 1];
                float a0 = uu[0] * wa.x;
                float a1 = uu[1] * wa.y;
                a0 = fmaf(uu[2], wa.z, a0);
                a1 = fmaf(uu[3], wa.w, a1);
                a0 = fmaf(uu[4], wb.x, a0);
                a1 = fmaf(uu[5], wb.y, a1);
                a0 = fmaf(uu[6], wb.z, a0);
                a1 = fmaf(uu[7], wb.w, a1);
                t[d][i] = a0 + a1;
            }
        }

        // register-cache W1 for this stage (used 15x: 8d x 5 iters x ...)
        float W1v[64];
        #pragma unroll
        for (int q = 0; q < 16; ++q) {
            float4 v = wlds4[(OFF_W1 + s * 64) / 4 + q];
            W1v[q * 4 + 0] = v.x; W1v[q * 4 + 1] = v.y;
            W1v[q * 4 + 2] = v.z; W1v[q * 4 + 3] = v.w;
        }
        float B1v[8];
        {
            float4 v0 = wlds4[(OFF_B1 + s * 8) / 4];
            float4 v1 = wlds4[(OFF_B1 + s * 8) / 4 + 1];
            B1v[0] = v0.x; B1v[1] = v0.y; B1v[2] = v0.z; B1v[3] = v0.w;
            B1v[4] = v1.x; B1v[5] = v1.y; B1v[6] = v1.z; B1v[7] = v1.w;
        }
        float B2v[4];
        {
            float4 v = wlds4[(OFF_B2 + s * 4) / 4];
            B2v[0] = v.x; B2v[1] = v.y; B2v[2] = v.z; B2v[3] = v.w;
        }

        for (int it = 0; it < NI; ++it) {
            // H[n][d] = C[n][d] + sum_i E[n][i]*t[d][i]   (Cs via LDS b128)
            float H[NE][D];
            #pragma unroll
            for (int n = 0; n < NE; ++n) {
                float4 c0 = wlds4[(OFF_C + s * 32 + n * 8) / 4];
                float4 c1 = wlds4[(OFF_C + s * 32 + n * 8) / 4 + 1];
                float cc[8] = { c0.x, c0.y, c0.z, c0.w, c1.x, c1.y, c1.z, c1.w };
                #pragma unroll
                for (int d = 0; d < D; ++d) {
                    float a0 = fmaf(E[n][0], t[d][0], cc[d]);
                    float a1 = E[n][1] * t[d][1];
                    a0 = fmaf(E[n][2], t[d][2], a0);
                    a1 = fmaf(E[n][3], t[d][3], a1);
                    a0 = fmaf(E[n][4], t[d][4], a0);
                    a1 = fmaf(E[n][5], t[d][5], a1);
                    a0 = fmaf(E[n][6], t[d][6], a0);
                    a1 = fmaf(E[n][7], t[d][7], a1);
                    H[n][d] = a0 + a1;
                }
            }
            // routing softmax per n (W1 in regs, W2 via LDS b128 broadcast)
            float sm[NE][NE];
            #pragma unroll
            for (int n = 0; n < NE; ++n) {
                float r[D];
                #pragma unroll
                for (int d = 0; d < D; ++d) {
                    float a0 = fmaf(H[n][0], W1v[d * 8 + 0], B1v[d]);
                    float a1 = H[n][1] * W1v[d * 8 + 1];
                    a0 = fmaf(H[n][2], W1v[d * 8 + 2], a0);
                    a1 = fmaf(H[n][3], W1v[d * 8 + 3], a1);
                    a0 = fmaf(H[n][4], W1v[d * 8 + 4], a0);
                    a1 = fmaf(H[n][5], W1v[d * 8 + 5], a1);
                    a0 = fmaf(H[n][6], W1v[d * 8 + 6], a0);
                    a1 = fmaf(H[n][7], W1v[d * 8 + 7], a1);
                    r[d] = fmaxf(a0 + a1, 0.f);
                }
                float lg[NE];
                #pragma unroll
                for (int e = 0; e < NE; ++e) {
                    float4 wa = wlds4[(OFF_W2 + s * 32 + e * 8) / 4];
                    float4 wb = wlds4[(OFF_W2 + s * 32 + e * 8) / 4 + 1];
                    float a0 = fmaf(r[0], wa.x, B2v[e]);
                    float a1 = r[1] * wa.y;
                    a0 = fmaf(r[2], wa.z, a0);
                    a1 = fmaf(r[3], wa.w, a1);
                    a0 = fmaf(r[4], wb.x, a0);
                    a1 = fmaf(r[5], wb.y, a1);
                    a0 = fmaf(r[6], wb.z, a0);
                    a1 = fmaf(r[7], wb.w, a1);
                    lg[e] = a0 + a1;
                }
                float mx = fmaxf(fmaxf(lg[0], lg[1]), fmaxf(lg[2], lg[3]));
                float e0 = __expf(lg[0] - mx), e1 = __expf(lg[1] - mx);
                float e2 = __expf(lg[2] - mx), e3 = __expf(lg[3] - mx);
                float inv = __builtin_amdgcn_rcpf((e0 + e1) + (e2 + e3));
                sm[n][0] = e0 * inv; sm[n][1] = e1 * inv;
                sm[n][2] = e2 * inv; sm[n][3] = e3 * inv;
            }
            // E += mix
            #pragma unroll
            for (int n = 0; n < NE; ++n) {
                #pragma unroll
                for (int d = 0; d < D; ++d) {
                    float a0 = fmaf(sm[n][0], H[0][d], E[n][d]);
                    float a1 = sm[n][1] * H[1][d];
                    a0 = fmaf(sm[n][2], H[2][d], a0);
                    a1 = fmaf(sm[n][3], H[3][d], a1);
                    E[n][d] = a0 + a1;
                }
            }
        }

        // post-stage LayerNorm (ln from LDS)
        float lngv[8], lnbv[8];
        {
            float4 g0 = wlds4[OFF_LNG / 4], g1 = wlds4[OFF_LNG / 4 + 1];
            float4 b0 = wlds4[OFF_LNB / 4], b1 = wlds4[OFF_LNB / 4 + 1];
            lngv[0]=g0.x; lngv[1]=g0.y; lngv[2]=g0.z; lngv[3]=g0.w;
            lngv[4]=g1.x; lngv[5]=g1.y; lngv[6]=g1.z; lngv[7]=g1.w;
            lnbv[0]=b0.x; lnbv[1]=b0.y; lnbv[2]=b0.z; lnbv[3]=b0.w;
            lnbv[4]=b1.x; lnbv[5]=b1.y; lnbv[6]=b1.z; lnbv[7]=b1.w;
        }
        #pragma unroll
        for (int n = 0; n < NE; ++n) {
            float m = 0.f;
            #pragma unroll
            for (int d = 0; d < D; ++d) m += E[n][d];
            m *= (1.f / D);
            float v = 0.f;
            #pragma unroll
            for (int d = 0; d < D; ++d) { float c = E[n][d] - m; v = fmaf(c, c, v); }
            v *= (1.f / D);
            float inv = __builtin_amdgcn_rsqf(v + LN_EPS);
            #pragma unroll
            for (int d = 0; d < D; ++d)
                E[n][d] = (E[n][d] - m) * inv * lngv[d] + lnbv[d];
        }
    }

    // ---- final mixing (Wout/bout via LDS) ----
    float lgf[NE];
    {
        float4 bo = wlds4[OFF_BOUT / 4];
        float bov[4] = { bo.x, bo.y, bo.z, bo.w };
        #pragma unroll
        for (int e = 0; e < NE; ++e) {
            float a0 = bov[e], a1 = 0.f;
            #pragma unroll
            for (int n = 0; n < NE; ++n) {
                float4 wa = wlds4[(OFF_WOUT + e * 32 + n * 8) / 4];
                float4 wb = wlds4[(OFF_WOUT + e * 32 + n * 8) / 4 + 1];
                a0 = fmaf(E[n][0], wa.x, a0);
                a1 = fmaf(E[n][1], wa.y, a1);
                a0 = fmaf(E[n][2], wa.z, a0);
                a1 = fmaf(E[n][3], wa.w, a1);
                a0 = fmaf(E[n][4], wb.x, a0);
                a1 = fmaf(E[n][5], wb.y, a1);
                a0 = fmaf(E[n][6], wb.z, a0);
                a1 = fmaf(E[n][7], wb.w, a1);
            }
            lgf[e] = a0 + a1;
        }
    }
    float mx = fmaxf(fmaxf(lgf[0], lgf[1]), fmaxf(lgf[2], lgf[3]));
    float w0 = __expf(lgf[0] - mx), w1 = __expf(lgf[1] - mx);
    float w2 = __expf(lgf[2] - mx), w3 = __expf(lgf[3] - mx);
    float winv = __builtin_amdgcn_rcpf((w0 + w1) + (w2 + w3));
    w0 *= winv; w1 *= winv; w2 *= winv; w3 *= winv;

    float z[D];
    #pragma unroll
    for (int d = 0; d < D; ++d) {
        float a0 = w0 * E[0][d];
        float a1 = w1 * E[1][d];
        a0 = fmaf(w2, E[2][d], a0);
        a1 = fmaf(w3, E[3][d], a1);
        z[d] = a0 + a1;
    }
    float zm = 0.f;
    #pragma unroll
    for (int d = 0; d < D; ++d) zm += z[d];
    zm *= (1.f / D);
    float zv = 0.f;
    #pragma unroll
    for (int d = 0; d < D; ++d) { float c = z[d] - zm; zv = fmaf(c, c, zv); }
    zv *= (1.f / D);
    float zinv = __builtin_amdgcn_rsqf(zv + LN_EPS);
    {
        float4 g0 = wlds4[OFF_FG / 4], g1 = wlds4[OFF_FG / 4 + 1];
        float4 b0 = wlds4[OFF_FB / 4], b1 = wlds4[OFF_FB / 4 + 1];
        float fgv[8] = { g0.x,g0.y,g0.z,g0.w,g1.x,g1.y,g1.z,g1.w };
        float fbv[8] = { b0.x,b0.y,b0.z,b0.w,b1.x,b1.y,b1.z,b1.w };
        #pragma unroll
        for (int d = 0; d < D; ++d)
            z[d] = (z[d] - zm) * zinv * fgv[d] + fbv[d];
    }

    // heads (Wcst/bcst/Wcl/bcl via LDS)
    float zout[19];
    #pragma unroll
    for (int k = 0; k < 18; ++k) {
        float4 wa = wlds4[(OFF_WCST + k * 8) / 4];
        float4 wb = wlds4[(OFF_WCST + k * 8) / 4 + 1];
        float a0 = fmaf(z[0], wa.x, wlds[OFF_BCST + k]);
        float a1 = z[1] * wa.y;
        a0 = fmaf(z[2], wa.z, a0);
        a1 = fmaf(z[3], wa.w, a1);
        a0 = fmaf(z[4], wb.x, a0);
        a1 = fmaf(z[5], wb.y, a1);
        a0 = fmaf(z[6], wb.z, a0);
        a1 = fmaf(z[7], wb.w, a1);
        zout[k] = a0 + a1;
    }
    {
        float4 wa = wlds4[OFF_WCL / 4];
        float4 wb = wlds4[OFF_WCL / 4 + 1];
        float a0 = fmaf(z[0], wa.x, wlds[OFF_BCL]);
        float a1 = z[1] * wa.y;
        a0 = fmaf(z[2], wa.z, a0);
        a1 = fmaf(z[3], wa.w, a1);
        a0 = fmaf(z[4], wb.x, a0);
        a1 = fmaf(z[5], wb.y, a1);
        a0 = fmaf(z[6], wb.z, a0);
        a1 = fmaf(z[7], wb.w, a1);
        zout[18] = a0 + a1;
    }

    if (active) {
        #pragma unroll
        for (int k = 0; k < 19; ++k) souts[tid * 19 + k] = zout[k];
    }
    __syncthreads();

    // coalesced writeback of this block's 256x19 outputs
    const int base = blockIdx.x * 256;
    int nrows = B - base;
    if (nrows > 256) nrows = 256;
    if (nrows > 0) {
        const int cnt = nrows * 19;
        for (int i = tid; i < cnt; i += 256)
            out[(size_t)base * 19 + i] = souts[i];
    }
}

extern "C" void kernel_launch(void* const* d_in, const int* in_sizes, int n_in,
                              void* d_out, int out_size, void* d_ws, size_t ws_size,
                              hipStream_t stream) {
    const float* cl     = (const float*)d_in[0];
    const float* cd     = (const float*)d_in[1];
    const float* re_log = (const float*)d_in[2];
    const float* mach   = (const float*)d_in[3];
    const float* alpha  = (const float*)d_in[4];
    const float* u      = (const float*)d_in[5];
    const float* We     = (const float*)d_in[6];
    const float* be     = (const float*)d_in[7];
    const float* Bmat   = (const float*)d_in[8];
    const float* Wproj  = (const float*)d_in[9];
    const float* bproj  = (const float*)d_in[10];
    const float* Wr1    = (const float*)d_in[11];
    const float* br1    = (const float*)d_in[12];
    const float* Wr2    = (const float*)d_in[13];
    const float* br2    = (const float*)d_in[14];
    const float* ln_g   = (const float*)d_in[15];
    const float* ln_b   = (const float*)d_in[16];
    const float* Wout   = (const float*)d_in[17];
    const float* bout   = (const float*)d_in[18];
    const float* fg     = (const float*)d_in[19];
    const float* fb     = (const float*)d_in[20];
    const float* Wcst   = (const float*)d_in[21];
    const float* bcst   = (const float*)d_in[22];
    const float* Wcl    = (const float*)d_in[23];
    const float* bcl    = (const float*)d_in[24];

    float* Cpre = (float*)d_ws;   // 96 floats
    const int B = in_sizes[0];

    hipLaunchKernelGGL(precompute_C_kernel, dim3(1), dim3(128), 0, stream,
                       Bmat, Wproj, bproj, Cpre);

    const int blocks = (B + 255) / 256;
    hipLaunchKernelGGL(whisp_kernel, dim3(blocks), dim3(256), 0, stream,
                       cl, cd, re_log, mach, alpha, u, We, be, Wproj,
                       Wr1, br1, Wr2, br2, ln_g, ln_b, Wout, bout, fg, fb,
                       Wcst, bcst, Wcl, bcl, Cpre, (float*)d_out, B);
}